// Round 8
// baseline (314.873 us; speedup 1.0000x reference)
//
#include <hip/hip_runtime.h>
#include <hip/hip_fp16.h>

#define B_   8
#define S_   4096
#define DD_  1024   // dst nodes
#define DIM_ 512
#define SCALE 0.044194173824159216f  // 1/sqrt(512)

typedef __bf16 bf16x8 __attribute__((ext_vector_type(8)));
typedef float  floatx4 __attribute__((ext_vector_type(4)));

__device__ inline unsigned short f2bf(float f) {
    union { float f; unsigned int u; } v; v.f = f;
    unsigned int r = v.u + 0x7fffu + ((v.u >> 16) & 1u);  // RNE
    return (unsigned short)(r >> 16);
}
__device__ inline float bf2f(unsigned short h) {
    union { unsigned int u; float f; } v; v.u = ((unsigned int)h) << 16;
    return v.f;
}
__device__ inline unsigned short f2h(float f) {
    __half h = __float2half(f);
    union { __half h; unsigned short u; } v; v.h = h; return v.u;
}
__device__ inline uint4 cvt8(const float* __restrict__ g) {
    float4 f0 = *(const float4*)g;
    float4 f1 = *(const float4*)(g + 4);
    unsigned short tmp[8] = {f2bf(f0.x), f2bf(f0.y), f2bf(f0.z), f2bf(f0.w),
                             f2bf(f1.x), f2bf(f1.y), f2bf(f1.z), f2bf(f1.w)};
    return *(const uint4*)tmp;
}
// async global->LDS, 16B per lane; lds base must be wave-uniform
__device__ inline void async16(unsigned short* lds, const unsigned short* g) {
    __builtin_amdgcn_global_load_lds(
        (const __attribute__((address_space(1))) void*)g,
        (__attribute__((address_space(3))) void*)lds, 16, 0, 0);
}

// ---------------------------------------------------------------------------
// 128x128xK mainloop, BK=32, 256 threads (2x2 waves, each 4x4 MFMA tiles).
// AF32/BF32: 1 = operand is fp32 (stage via cvt8 store), 0 = bf16 (async16).
// ---------------------------------------------------------------------------
template <int AF32, int BF32>
__device__ inline void mainloop(unsigned short* As, unsigned short* Bs,
                                const void* Ap, size_t lda,
                                const void* Bp, size_t ldb,
                                int kIters, floatx4 (&acc)[4][4]) {
    const int t = threadIdx.x, lane = t & 63, wave = t >> 6;
    const int rA = t >> 2, cA = (t & 3) * 8;
    const int mrow = (wave >> 1) * 64, ncol = (wave & 1) * 64;
    const int fr = lane & 15, fk = (lane >> 4) * 8;

    const unsigned short* gA16 = nullptr; const float* gA32 = nullptr;
    const unsigned short* gB16 = nullptr; const float* gB32 = nullptr;
    if (AF32) gA32 = (const float*)Ap + (size_t)rA * lda + cA;
    else      gA16 = (const unsigned short*)Ap + (size_t)rA * lda + cA;
    if (BF32) gB32 = (const float*)Bp + (size_t)rA * ldb + cA;
    else      gB16 = (const unsigned short*)Bp + (size_t)rA * ldb + cA;

    unsigned short* ldsA = As + wave * 512;   // halfwords; second 64 rows at +2048
    unsigned short* ldsB = Bs + wave * 512;

    for (int kt = 0; kt < kIters; ++kt) {
        if (AF32) {
            *(uint4*)&As[t * 8]        = cvt8(gA32);
            *(uint4*)&As[2048 + t * 8] = cvt8(gA32 + 64 * lda);
            gA32 += 32;
        } else {
            async16(ldsA,        gA16);
            async16(ldsA + 2048, gA16 + 64 * lda);
            gA16 += 32;
        }
        if (BF32) {
            *(uint4*)&Bs[t * 8]        = cvt8(gB32);
            *(uint4*)&Bs[2048 + t * 8] = cvt8(gB32 + 64 * ldb);
            gB32 += 32;
        } else {
            async16(ldsB,        gB16);
            async16(ldsB + 2048, gB16 + 64 * ldb);
            gB16 += 32;
        }
        __syncthreads();
        bf16x8 af[4], bfr[4];
#pragma unroll
        for (int i = 0; i < 4; ++i)
            af[i] = *(const bf16x8*)&As[(mrow + i * 16 + fr) * 32 + fk];
#pragma unroll
        for (int j = 0; j < 4; ++j)
            bfr[j] = *(const bf16x8*)&Bs[(ncol + j * 16 + fr) * 32 + fk];
#pragma unroll
        for (int i = 0; i < 4; ++i)
#pragma unroll
            for (int j = 0; j < 4; ++j)
                acc[i][j] = __builtin_amdgcn_mfma_f32_16x16x32_bf16(af[i], bfr[j],
                                                                    acc[i][j], 0, 0, 0);
        __syncthreads();
    }
}

#define EPILOGUE_COORDS                                     \
    const int lane = threadIdx.x & 63, wave = threadIdx.x >> 6; \
    const int mrow = (wave >> 1) * 64, ncol = (wave & 1) * 64;  \
    const int col = lane & 15, q = lane >> 4;

#define ACC_INIT                                            \
    floatx4 acc[4][4];                                      \
    _Pragma("unroll") for (int i = 0; i < 4; ++i)           \
        _Pragma("unroll") for (int j = 0; j < 4; ++j)       \
            acc[i][j] = (floatx4){0.f, 0.f, 0.f, 0.f};

// ---------------------------------------------------------------------------
// k_prep: blocks [0,8192): srcb = bf16(src); [8192,10240): dstb = bf16(dst)
// ---------------------------------------------------------------------------
__global__ __launch_bounds__(256) void k_prep(const float* __restrict__ src,
                                              unsigned short* __restrict__ srcb,
                                              const float* __restrict__ dst,
                                              unsigned short* __restrict__ dstb) {
    const int t = threadIdx.x;
    if (blockIdx.x < 8192) {
        const size_t idx = ((size_t)blockIdx.x * 256 + t) * 8;
        *(uint4*)&srcb[idx] = cvt8(src + idx);
    } else {
        const size_t idx = ((size_t)(blockIdx.x - 8192) * 256 + t) * 8;
        *(uint4*)&dstb[idx] = cvt8(dst + idx);
    }
}

// ---------------------------------------------------------------------------
// k_dstWr: DW[b*dd][d] = SCALE * sum_e dstb[b*dd][e] * Wr[d][e]
// ---------------------------------------------------------------------------
__global__ __launch_bounds__(256) void k_dstWr(const unsigned short* __restrict__ dstb,
                                               const float* __restrict__ Wr,
                                               unsigned short* __restrict__ DW) {
    __shared__ unsigned short As[128 * 32];
    __shared__ unsigned short Bs[128 * 32];
    const int n0 = blockIdx.x * 128, m0 = blockIdx.y * 128;
    ACC_INIT
    mainloop<0, 1>(As, Bs, dstb + (size_t)m0 * DIM_, DIM_,
                   Wr + (size_t)n0 * DIM_, DIM_, DIM_ / 32, acc);
    EPILOGUE_COORDS
#pragma unroll
    for (int i = 0; i < 4; ++i)
#pragma unroll
        for (int j = 0; j < 4; ++j)
#pragma unroll
            for (int r = 0; r < 4; ++r)
                DW[(size_t)(m0 + mrow + i * 16 + q * 4 + r) * DIM_ +
                   n0 + ncol + j * 16 + col] = f2bf(acc[i][j][r] * SCALE);
}

// ---------------------------------------------------------------------------
// k_logitsT: LT[dd][s] = exp(DW[dd][:] . srcb[s][:]) -> bf16  (per batch)
// XCD swizzle: xcd = b. Epilogue: LDS repack (stride-136 pad) -> uint4 stores;
// per-(b, dd-tile) column sums Lpart (fp32).
// ---------------------------------------------------------------------------
__global__ __launch_bounds__(256) void k_logitsT(const unsigned short* __restrict__ DW,
                                                 const unsigned short* __restrict__ srcb,
                                                 unsigned short* __restrict__ LTb,
                                                 float* __restrict__ Lpart) {
    __shared__ unsigned short As[128 * 32];
    __shared__ unsigned short Bs[128 * 32];
    __shared__ __align__(16) unsigned short Rep[64 * 136];
    __shared__ float csum[8][128];
    const int n = blockIdx.x;
    const int b = n & 7;          // -> XCD
    const int rem = n >> 3;       // [0,256)
    const int xs = rem >> 3;      // s-tile [0,32), changes slowly (B hot)
    const int yd = rem & 7;       // dd-tile [0,8)
    const int n0 = xs * 128, m0 = yd * 128;
    ACC_INIT
    mainloop<0, 0>(As, Bs,
                   DW + (size_t)b * DD_ * DIM_ + (size_t)m0 * DIM_, DIM_,
                   srcb + (size_t)b * S_ * DIM_ + (size_t)n0 * DIM_, DIM_,
                   DIM_ / 32, acc);
    EPILOGUE_COORDS
    const int t = threadIdx.x;
    unsigned short* LT = LTb + (size_t)b * DD_ * S_;
    float psum[4] = {0.f, 0.f, 0.f, 0.f};
    const int myp = wave >> 1;            // which 64-row half this wave owns
    const int rrow = t >> 2, rcg = (t & 3) * 32;

    // round 0: waves 0-1 (rows 0-63) exp -> Rep; then all copy out
    if (myp == 0) {
#pragma unroll
        for (int i = 0; i < 4; ++i)
#pragma unroll
            for (int j = 0; j < 4; ++j)
#pragma unroll
                for (int r = 0; r < 4; ++r) {
                    float e = __expf(acc[i][j][r]);
                    Rep[(i * 16 + q * 4 + r) * 136 + ncol + j * 16 + col] = f2bf(e);
                    psum[j] += e;
                }
    }
    __syncthreads();
    {
        unsigned short* o = LT + (size_t)(m0 + rrow) * S_ + n0 + rcg;
        const unsigned short* rp = &Rep[rrow * 136 + rcg];
#pragma unroll
        for (int k = 0; k < 4; ++k) *(uint4*)(o + k * 8) = *(const uint4*)(rp + k * 8);
    }
    __syncthreads();
    // round 1: waves 2-3 (rows 64-127)
    if (myp == 1) {
#pragma unroll
        for (int i = 0; i < 4; ++i)
#pragma unroll
            for (int j = 0; j < 4; ++j)
#pragma unroll
                for (int r = 0; r < 4; ++r) {
                    float e = __expf(acc[i][j][r]);
                    Rep[(i * 16 + q * 4 + r) * 136 + ncol + j * 16 + col] = f2bf(e);
                    psum[j] += e;
                }
    }
    __syncthreads();
    {
        unsigned short* o = LT + (size_t)(m0 + 64 + rrow) * S_ + n0 + rcg;
        const unsigned short* rp = &Rep[rrow * 136 + rcg];
#pragma unroll
        for (int k = 0; k < 4; ++k) *(uint4*)(o + k * 8) = *(const uint4*)(rp + k * 8);
    }
    const int slice = myp * 4 + q;
#pragma unroll
    for (int j = 0; j < 4; ++j) csum[slice][ncol + j * 16 + col] = psum[j];
    __syncthreads();
    if (t < 128) {
        float v = 0.f;
#pragma unroll
        for (int k = 0; k < 8; ++k) v += csum[k][t];
        Lpart[((size_t)b * 8 + yd) * S_ + n0 + t] = v;
    }
}

// ---------------------------------------------------------------------------
// k_finalize: scale = softplus(state)/denom; wst = scale*state
// (both park in d_out's d_val region — overwritten by k_dvalW at the end)
// ---------------------------------------------------------------------------
__global__ __launch_bounds__(256) void k_finalize(const float* __restrict__ state,
                                                  const float* __restrict__ Lpart,
                                                  float* __restrict__ scale,
                                                  float* __restrict__ wst) {
    const int i = blockIdx.x * 256 + threadIdx.x;    // flat b*S+s
    const int b = i >> 12, s = i & (S_ - 1);
    float d = 0.f;
#pragma unroll
    for (int k = 0; k < 8; ++k) d += Lpart[((size_t)b * 8 + k) * S_ + s];
    const float st = state[i];
    const float sp = (st > 15.f) ? st : log1pf(__expf(st));
    const float sc = sp / d;
    scale[i] = sc;
    wst[i] = sc * st;
}

// ---------------------------------------------------------------------------
// k_srcT: srcST[b][d'][s] = bf16( scale[b][s] * srcb[b][s][d'] )
// ---------------------------------------------------------------------------
__global__ __launch_bounds__(256) void k_srcT(const unsigned short* __restrict__ srcb,
                                              const float* __restrict__ scale,
                                              unsigned short* __restrict__ srcST) {
    __shared__ unsigned short Ts[64 * 65];
    const int s0 = blockIdx.x * 64, d0 = blockIdx.y * 64, b = blockIdx.z;
    const int t = threadIdx.x;
    {
        const int r = t >> 2, c0 = (t & 3) * 16;   // r = s-local, c = d'-local
        const unsigned short* g =
            srcb + (size_t)b * S_ * DIM_ + (size_t)(s0 + r) * DIM_ + d0 + c0;
        uint4 v0 = *(const uint4*)g;
        uint4 v1 = *(const uint4*)(g + 8);
        const unsigned short* e0 = (const unsigned short*)&v0;
        const unsigned short* e1 = (const unsigned short*)&v1;
        const float sc = scale[(size_t)b * S_ + s0 + r];
#pragma unroll
        for (int i = 0; i < 8; ++i) {
            Ts[r * 65 + c0 + i]     = f2bf(bf2f(e0[i]) * sc);
            Ts[r * 65 + c0 + 8 + i] = f2bf(bf2f(e1[i]) * sc);
        }
    }
    __syncthreads();
    {
        const int rr = t >> 2, c0 = (t & 3) * 16;  // rr = d'-local, c = s-local
        unsigned short tmp[16];
#pragma unroll
        for (int j = 0; j < 16; ++j) tmp[j] = Ts[(c0 + j) * 65 + rr];
        unsigned short* o =
            srcST + (size_t)b * DIM_ * S_ + (size_t)(d0 + rr) * S_ + s0 + c0;
        *(uint4*)o = *(const uint4*)tmp;
        *(uint4*)(o + 8) = *(const uint4*)(tmp + 8);
    }
}

// ---------------------------------------------------------------------------
// k_dU: partial[ks][b][dd][d'] = sum_{s slice} LT[dd][s]*srcST[d'][s], fp16
// split-K=4; XCD pin per z=(b,ks). xe==0 blocks also fold the dstate GEMV:
// Dp[b][ks][dd] = sum_{s slice} LT[dd][s]*wst[s]  (LT tile already in LDS).
// Epilogue: LDS repack -> uint4 stores.
// ---------------------------------------------------------------------------
__global__ __launch_bounds__(256) void k_dU(const unsigned short* __restrict__ LTb,
                                            const unsigned short* __restrict__ srcST,
                                            const float* __restrict__ wst,
                                            __half* __restrict__ Pp,
                                            float* __restrict__ Dp) {
    __shared__ unsigned short As[128 * 32];
    __shared__ unsigned short Bs[128 * 32];
    __shared__ __align__(16) unsigned short Rep[64 * 136];
    __shared__ float wlds[1024];
    const int n = blockIdx.x;
    const int z = (n & 7) + 8 * (n >> 8);   // [0,32): (b,ks) -> XCD = n&7
    const int rem = (n >> 3) & 31;
    const int xe = rem >> 3;                // d'-tile [0,4)
    const int yd = rem & 7;                 // dd-tile [0,8)
    const int b = z >> 2, ks = z & 3;
    const int n0 = xe * 128, m0 = yd * 128;
    const int t = threadIdx.x, lane = t & 63, wave = t >> 6;
    const int rA = t >> 2, cA = (t & 3) * 8;
    const int mrow = (wave >> 1) * 64, ncol = (wave & 1) * 64;
    const int fr = lane & 15, fk = (lane >> 4) * 8;
    const bool dofold = (xe == 0);
    if (dofold)
        *(float4*)&wlds[t * 4] =
            *(const float4*)(wst + (size_t)b * S_ + ks * 1024 + t * 4);

    ACC_INIT
    const unsigned short* gA =
        LTb + (size_t)b * DD_ * S_ + (size_t)(m0 + rA) * S_ + ks * 1024 + cA;
    const unsigned short* gB =
        srcST + (size_t)b * DIM_ * S_ + (size_t)(n0 + rA) * S_ + ks * 1024 + cA;
    unsigned short* ldsA = As + wave * 512;
    unsigned short* ldsB = Bs + wave * 512;
    float dacc = 0.f;
    const int drow = t >> 1, dkh = (t & 1) * 16;

    for (int kt = 0; kt < 32; ++kt) {
        async16(ldsA,        gA);
        async16(ldsA + 2048, gA + 64 * S_);
        async16(ldsB,        gB);
        async16(ldsB + 2048, gB + 64 * S_);
        gA += 32; gB += 32;
        __syncthreads();
        bf16x8 af[4], bfr[4];
#pragma unroll
        for (int i = 0; i < 4; ++i)
            af[i] = *(const bf16x8*)&As[(mrow + i * 16 + fr) * 32 + fk];
#pragma unroll
        for (int j = 0; j < 4; ++j)
            bfr[j] = *(const bf16x8*)&Bs[(ncol + j * 16 + fr) * 32 + fk];
#pragma unroll
        for (int i = 0; i < 4; ++i)
#pragma unroll
            for (int j = 0; j < 4; ++j)
                acc[i][j] = __builtin_amdgcn_mfma_f32_16x16x32_bf16(af[i], bfr[j],
                                                                    acc[i][j], 0, 0, 0);
        if (dofold) {
            bf16x8 v0 = *(const bf16x8*)&As[drow * 32 + dkh];
            bf16x8 v1 = *(const bf16x8*)&As[drow * 32 + dkh + 8];
            const float* wp = &wlds[kt * 32 + dkh];
            float p = 0.f;
#pragma unroll
            for (int jj = 0; jj < 8; ++jj)
                p += (float)v0[jj] * wp[jj] + (float)v1[jj] * wp[jj + 8];
            dacc += p;
        }
        __syncthreads();
    }
    if (dofold) {
        dacc += __shfl_xor(dacc, 1);
        if (!(t & 1)) Dp[((size_t)(b * 4 + ks)) * 1024 + m0 + drow] = dacc;
    }

    // epilogue: two-round LDS repack -> coalesced uint4 stores (fp16)
    unsigned short* O = (unsigned short*)Pp + (size_t)ks * B_ * DD_ * DIM_ +
                        (size_t)b * DD_ * DIM_;
    const int col = fr, q = lane >> 4;
    const int myp = wave >> 1;
    const int rrow = t >> 2, rcg = (t & 3) * 32;
    if (myp == 0) {
#pragma unroll
        for (int i = 0; i < 4; ++i)
#pragma unroll
            for (int j = 0; j < 4; ++j)
#pragma unroll
                for (int r = 0; r < 4; ++r)
                    Rep[(i * 16 + q * 4 + r) * 136 + ncol + j * 16 + col] =
                        f2h(acc[i][j][r]);
    }
    __syncthreads();
    {
        unsigned short* o = O + (size_t)(m0 + rrow) * DIM_ + n0 + rcg;
        const unsigned short* rp = &Rep[rrow * 136 + rcg];
#pragma unroll
        for (int k = 0; k < 4; ++k) *(uint4*)(o + k * 8) = *(const uint4*)(rp + k * 8);
    }
    __syncthreads();
    if (myp == 1) {
#pragma unroll
        for (int i = 0; i < 4; ++i)
#pragma unroll
            for (int j = 0; j < 4; ++j)
#pragma unroll
                for (int r = 0; r < 4; ++r)
                    Rep[(i * 16 + q * 4 + r) * 136 + ncol + j * 16 + col] =
                        f2h(acc[i][j][r]);
    }
    __syncthreads();
    {
        unsigned short* o = O + (size_t)(m0 + 64 + rrow) * DIM_ + n0 + rcg;
        const unsigned short* rp = &Rep[rrow * 136 + rcg];
#pragma unroll
        for (int k = 0; k < 4; ++k) *(uint4*)(o + k * 8) = *(const uint4*)(rp + k * 8);
    }
}

// ---------------------------------------------------------------------------
// k_reduceU: [0,2048): U bf16 = sum of 4 fp16 partial slices
//            [2048,2112): WvT[e][d] = bf16(Wv[d][e]) transpose
//            [2112,2144): d_state[b][dd] = sum_ks Dp[b][ks][dd]
// ---------------------------------------------------------------------------
__global__ __launch_bounds__(256) void k_reduceU(const __half* __restrict__ Pp,
                                                 unsigned short* __restrict__ U,
                                                 const float* __restrict__ Wv,
                                                 unsigned short* __restrict__ WvT,
                                                 const float* __restrict__ Dp,
                                                 float* __restrict__ d_state) {
    __shared__ float Ts[64 * 68];
    const int t = threadIdx.x;
    if (blockIdx.x < 2048) {
        const size_t idx = ((size_t)blockIdx.x * 256 + t) * 8;
        const size_t n = (size_t)B_ * DD_ * DIM_;
        float o[8] = {0.f, 0.f, 0.f, 0.f, 0.f, 0.f, 0.f, 0.f};
#pragma unroll
        for (int ks = 0; ks < 4; ++ks) {
            uint4 v = *(const uint4*)(Pp + (size_t)ks * n + idx);
            const __half* h = (const __half*)&v;
#pragma unroll
            for (int j = 0; j < 8; ++j) o[j] += __half2float(h[j]);
        }
        unsigned short tmp[8];
#pragma unroll
        for (int j = 0; j < 8; ++j) tmp[j] = f2bf(o[j]);
        *(uint4*)&U[idx] = *(const uint4*)tmp;
        return;
    }
    if (blockIdx.x >= 2112) {
        const int flat = (blockIdx.x - 2112) * 256 + t;   // [0, 8192)
        const int bb = flat >> 10, dd = flat & 1023;
        float v = 0.f;
#pragma unroll
        for (int ks = 0; ks < 4; ++ks) v += Dp[((size_t)(bb * 4 + ks)) * 1024 + dd];
        d_state[(size_t)bb * DD_ + dd] = v;
        return;
    }
    const int n2 = blockIdx.x - 2048;
    const int d0 = (n2 & 7) * 64, e0 = (n2 >> 3) * 64;
    {
        const int r = t >> 2, c0 = (t & 3) * 16;
        const float* g = Wv + (size_t)(d0 + r) * DIM_ + e0 + c0;
#pragma unroll
        for (int i = 0; i < 4; ++i)
            *(float4*)&Ts[r * 68 + c0 + i * 4] = *(const float4*)(g + i * 4);
    }
    __syncthreads();
    {
        const int rr = t >> 2, c0 = (t & 3) * 16;
        unsigned short tmp[16];
#pragma unroll
        for (int j = 0; j < 16; ++j) tmp[j] = f2bf(Ts[(c0 + j) * 68 + rr]);
        unsigned short* o = WvT + (size_t)(e0 + rr) * DIM_ + d0 + c0;
        *(uint4*)o = *(const uint4*)tmp;
        *(uint4*)(o + 8) = *(const uint4*)(tmp + 8);
    }
}

// ---------------------------------------------------------------------------
// k_dvalW: d_val[b*dd][e] = sum_d' U[b*dd][d'] * WvT[e][d']   (fp32 out)
// ---------------------------------------------------------------------------
__global__ __launch_bounds__(256) void k_dvalW(const unsigned short* __restrict__ U,
                                               const unsigned short* __restrict__ WvT,
                                               float* __restrict__ d_val) {
    __shared__ unsigned short As[128 * 32];
    __shared__ unsigned short Bs[128 * 32];
    const int n0 = blockIdx.x * 128, m0 = blockIdx.y * 128;
    ACC_INIT
    mainloop<0, 0>(As, Bs, U + (size_t)m0 * DIM_, DIM_,
                   WvT + (size_t)n0 * DIM_, DIM_, DIM_ / 32, acc);
    EPILOGUE_COORDS
#pragma unroll
    for (int i = 0; i < 4; ++i)
#pragma unroll
        for (int j = 0; j < 4; ++j)
#pragma unroll
            for (int r = 0; r < 4; ++r)
                d_val[(size_t)(m0 + mrow + i * 16 + q * 4 + r) * DIM_ +
                      n0 + ncol + j * 16 + col] = acc[i][j][r];
}

// ---------------------------------------------------------------------------
extern "C" void kernel_launch(void* const* d_in, const int* in_sizes, int n_in,
                              void* d_out, int out_size, void* d_ws, size_t ws_size,
                              hipStream_t stream) {
    const float* src   = (const float*)d_in[0];   // [B,S,DIM]
    const float* state = (const float*)d_in[1];   // [B,S]
    const float* dst   = (const float*)d_in[2];   // [B,D,DIM]
    const float* Wr    = (const float*)d_in[3];   // [DIM,DIM]
    const float* Wv    = (const float*)d_in[4];   // [DIM,DIM]

    // ws layout (128 MiB):
    //  A [0,32):  srcb bf16 (prep -> srcT/logitsT); late: Pp fp16 4x8MiB
    //  B [32,96): LT bf16 (logitsT -> dU); late: U bf16 (8) + WvT (.5)
    //  C [96,128): early: dstb(8) DW(8) Lpart(1); late: srcST (32)
    //  scale/wst/Dp park in d_out's d_val region (dead before k_dvalW writes)
    unsigned short* srcb = (unsigned short*)d_ws;
    __half* Pp = (__half*)d_ws;
    unsigned short* LT = srcb + (size_t)B_ * S_ * DIM_;
    unsigned short* U  = LT;                                   // overlays dead LT
    unsigned short* WvT = U + (size_t)B_ * DD_ * DIM_;
    unsigned short* C = LT + (size_t)B_ * DD_ * S_;
    unsigned short* dstb = C;
    unsigned short* DW = dstb + (size_t)B_ * DD_ * DIM_;
    float* Lpart = (float*)(DW + (size_t)B_ * DD_ * DIM_);     // [B][8][S]
    unsigned short* srcST = C;                                 // overlays dead dstb/DW/Lpart

    float* d_state = (float*)d_out;               // [B, DD]
    float* d_val   = (float*)d_out + B_ * DD_;    // [B, DD, DIM]
    float* scale   = d_val;                       // parked, dead before k_dvalW
    float* wst     = d_val + (size_t)B_ * S_;
    float* Dp      = d_val + 2 * (size_t)B_ * S_; // [B][4][1024]

    k_prep<<<dim3(8192 + 2048), 256, 0, stream>>>(src, srcb, dst, dstb);
    k_dstWr<<<dim3(DIM_ / 128, (B_ * DD_) / 128), 256, 0, stream>>>(dstb, Wr, DW);
    k_logitsT<<<dim3(2048), 256, 0, stream>>>(DW, srcb, LT, Lpart);
    k_finalize<<<dim3((B_ * S_) / 256), 256, 0, stream>>>(state, Lpart, scale, wst);
    k_srcT<<<dim3(S_ / 64, DIM_ / 64, B_), 256, 0, stream>>>(srcb, scale, srcST);
    k_dU<<<dim3(1024), 256, 0, stream>>>(LT, srcST, wst, Pp, Dp);
    k_reduceU<<<dim3(2048 + 64 + 32), 256, 0, stream>>>(Pp, U, Wv, WvT, Dp, d_state);
    k_dvalW<<<dim3(DIM_ / 128, (B_ * DD_) / 128), 256, 0, stream>>>(U, WvT, d_val);
}